// Round 2
// baseline (3022.877 us; speedup 1.0000x reference)
//
#include <hip/hip_runtime.h>

#define NNODES 50000
#define NEDGES 800000
#define HIDDIM 256

constexpr float kAlpha = 0.1f;          // initial-residual weight
constexpr float kBnEps = 1e-5f;
constexpr float kBeta  = 0.40546510810816438198f;   // log(1.5)

// ---------------------------------------------------------------------------
// GEMM: C = A[nrows,256] @ B[256,256]  (64x64 tile, 4x4 microtile, fp32)
// MODE 0: also accumulate per-column sum / sumsq (for BatchNorm) via one
//         block-level reduction + 2 atomics per column per block.
// MODE 1: GCNII epilogue: C = relu((1-beta)*A + beta*(A@B))
// ---------------------------------------------------------------------------
template<int MODE>
__global__ __launch_bounds__(256) void gemm_k(const float* __restrict__ A,
                                              const float* __restrict__ B,
                                              float* __restrict__ C,
                                              float* __restrict__ colsum,
                                              float* __restrict__ colsumsq,
                                              int nrows) {
  __shared__ float As[128][64];        // A-tile, transposed: As[k][row]  (32 KB)
  __shared__ float red[2][16][64];     // column-stat reduction (MODE 0), 8 KB

  const int t  = threadIdx.x;
  const int tx = t & 15;               // column group (4 cols each)
  const int ty = t >> 4;               // row group (4 rows each), 0..15
  const long long row0 = (long long)blockIdx.x * 64;
  const int col0 = blockIdx.y * 64;

  float acc[4][4];
#pragma unroll
  for (int i = 0; i < 4; ++i)
#pragma unroll
    for (int j = 0; j < 4; ++j) acc[i][j] = 0.f;

  // staging assignment: thread -> (row sr, k-offset sk)
  const int sr = t >> 2;               // 0..63
  const int sk = (t & 3) * 4;          // 0,4,8,12
  const bool srow_ok = (row0 + sr) < nrows;
  const float* Arow = A + (row0 + sr) * HIDDIM;

  for (int half = 0; half < 2; ++half) {
    if (half) __syncthreads();         // protect As before overwrite
    // stage 128 k-slices of the A-tile, transposed (zero-pad OOB rows)
#pragma unroll
    for (int kb = 0; kb < 128; kb += 16) {
      float4 v = make_float4(0.f, 0.f, 0.f, 0.f);
      if (srow_ok) v = *(const float4*)(Arow + half * 128 + kb + sk);
      As[kb + sk + 0][sr] = v.x;
      As[kb + sk + 1][sr] = v.y;
      As[kb + sk + 2][sr] = v.z;
      As[kb + sk + 3][sr] = v.w;
    }
    __syncthreads();

    const float* Bp = B + (half * 128) * HIDDIM + col0 + tx * 4;
#pragma unroll 4
    for (int k = 0; k < 128; ++k) {
      float4 a = *(const float4*)&As[k][ty * 4];     // broadcast, conflict-free
      float4 b = *(const float4*)(Bp + k * HIDDIM);  // 256B/wave, L1/L2-hot
      acc[0][0] = fmaf(a.x, b.x, acc[0][0]);
      acc[0][1] = fmaf(a.x, b.y, acc[0][1]);
      acc[0][2] = fmaf(a.x, b.z, acc[0][2]);
      acc[0][3] = fmaf(a.x, b.w, acc[0][3]);
      acc[1][0] = fmaf(a.y, b.x, acc[1][0]);
      acc[1][1] = fmaf(a.y, b.y, acc[1][1]);
      acc[1][2] = fmaf(a.y, b.z, acc[1][2]);
      acc[1][3] = fmaf(a.y, b.w, acc[1][3]);
      acc[2][0] = fmaf(a.z, b.x, acc[2][0]);
      acc[2][1] = fmaf(a.z, b.y, acc[2][1]);
      acc[2][2] = fmaf(a.z, b.z, acc[2][2]);
      acc[2][3] = fmaf(a.z, b.w, acc[2][3]);
      acc[3][0] = fmaf(a.w, b.x, acc[3][0]);
      acc[3][1] = fmaf(a.w, b.y, acc[3][1]);
      acc[3][2] = fmaf(a.w, b.z, acc[3][2]);
      acc[3][3] = fmaf(a.w, b.w, acc[3][3]);
    }
  }

  // ---- epilogue ----
#pragma unroll
  for (int i = 0; i < 4; ++i) {
    long long r = row0 + ty * 4 + i;
    if (r < nrows) {
      float4 o;
      if (MODE == 0) {
        o = make_float4(acc[i][0], acc[i][1], acc[i][2], acc[i][3]);
      } else {
        float4 s = *(const float4*)(A + r * HIDDIM + col0 + tx * 4);
        o.x = fmaxf((1.f - kBeta) * s.x + kBeta * acc[i][0], 0.f);
        o.y = fmaxf((1.f - kBeta) * s.y + kBeta * acc[i][1], 0.f);
        o.z = fmaxf((1.f - kBeta) * s.z + kBeta * acc[i][2], 0.f);
        o.w = fmaxf((1.f - kBeta) * s.w + kBeta * acc[i][3], 0.f);
      }
      *(float4*)(C + r * HIDDIM + col0 + tx * 4) = o;
    }
  }

  if (MODE == 0) {
    // per-thread column partials (OOB rows contributed exact zeros)
#pragma unroll
    for (int j = 0; j < 4; ++j) {
      float s  = acc[0][j] + acc[1][j] + acc[2][j] + acc[3][j];
      float s2 = acc[0][j] * acc[0][j] + acc[1][j] * acc[1][j] +
                 acc[2][j] * acc[2][j] + acc[3][j] * acc[3][j];
      red[0][ty][tx * 4 + j] = s;
      red[1][ty][tx * 4 + j] = s2;
    }
    __syncthreads();
    if (t < 64) {
      float ssum = 0.f, s2sum = 0.f;
#pragma unroll
      for (int g = 0; g < 16; ++g) {
        ssum  += red[0][g][t];
        s2sum += red[1][g][t];
      }
      atomicAdd(&colsum[col0 + t], ssum);
      atomicAdd(&colsumsq[col0 + t], s2sum);
    }
  }
}

// ---------------------------------------------------------------------------
// BatchNorm finalize: scale/shift per column
// ---------------------------------------------------------------------------
__global__ __launch_bounds__(256) void bn_finalize_k(const float* __restrict__ colsum,
                                                     const float* __restrict__ colsumsq,
                                                     const float* __restrict__ gamma,
                                                     const float* __restrict__ beta_bn,
                                                     float* __restrict__ scale,
                                                     float* __restrict__ shift) {
  int j = threadIdx.x;
  float inv_n = 1.0f / (float)NNODES;
  float mu  = colsum[j] * inv_n;
  float var = colsumsq[j] * inv_n - mu * mu;
  float rstd = rsqrtf(var + kBnEps);
  float sc = gamma[j] * rstd;
  scale[j] = sc;
  shift[j] = beta_bn[j] - mu * sc;
}

// ---------------------------------------------------------------------------
// In-place BN-apply + ReLU on h
// ---------------------------------------------------------------------------
__global__ __launch_bounds__(256) void bn_relu_k(float* __restrict__ h,
                                                 const float* __restrict__ scale,
                                                 const float* __restrict__ shift) {
  const int n4 = NNODES * HIDDIM / 4;
  int stride = gridDim.x * blockDim.x;
  for (int i = blockIdx.x * blockDim.x + threadIdx.x; i < n4; i += stride) {
    float4 v = ((const float4*)h)[i];
    int c = (i << 2) & (HIDDIM - 1);
    v.x = fmaxf(fmaf(v.x, scale[c + 0], shift[c + 0]), 0.f);
    v.y = fmaxf(fmaf(v.y, scale[c + 1], shift[c + 1]), 0.f);
    v.z = fmaxf(fmaf(v.z, scale[c + 2], shift[c + 2]), 0.f);
    v.w = fmaxf(fmaf(v.w, scale[c + 3], shift[c + 3]), 0.f);
    ((float4*)h)[i] = v;
  }
}

// ---------------------------------------------------------------------------
// Edge scatter-add: agg[dst] += h[src]   (one 64-lane wave per edge)
// ---------------------------------------------------------------------------
__global__ __launch_bounds__(256) void scatter_k(const float* __restrict__ h,
                                                 const int* __restrict__ ei,
                                                 float* __restrict__ agg) {
  const int lane = threadIdx.x & 63;
  const int w = threadIdx.x >> 6;
  long long e = (long long)blockIdx.x * 4 + w;
  if (e >= NEDGES) return;
  const int s = ei[e];
  const int d = ei[NEDGES + e];
  float4 v = *(const float4*)(h + (long long)s * HIDDIM + lane * 4);
  float* o = agg + (long long)d * HIDDIM + lane * 4;
  atomicAdd(o + 0, v.x);
  atomicAdd(o + 1, v.y);
  atomicAdd(o + 2, v.z);
  atomicAdd(o + 3, v.w);
}

// ---------------------------------------------------------------------------
// support = 0.9*(h + agg) + 0.1*x0   (in-place into agg)
// ---------------------------------------------------------------------------
__global__ __launch_bounds__(256) void support_k(const float* __restrict__ h,
                                                 float* __restrict__ agg,
                                                 const float* __restrict__ x0) {
  const int n4 = NNODES * HIDDIM / 4;
  int stride = gridDim.x * blockDim.x;
  for (int i = blockIdx.x * blockDim.x + threadIdx.x; i < n4; i += stride) {
    float4 a  = ((const float4*)agg)[i];
    float4 hh = ((const float4*)h)[i];
    float4 x  = ((const float4*)x0)[i];
    float4 o;
    o.x = (1.f - kAlpha) * (hh.x + a.x) + kAlpha * x.x;
    o.y = (1.f - kAlpha) * (hh.y + a.y) + kAlpha * x.y;
    o.z = (1.f - kAlpha) * (hh.z + a.z) + kAlpha * x.z;
    o.w = (1.f - kAlpha) * (hh.w + a.w) + kAlpha * x.w;
    ((float4*)agg)[i] = o;
  }
}

// ---------------------------------------------------------------------------
extern "C" void kernel_launch(void* const* d_in, const int* in_sizes, int n_in,
                              void* d_out, int out_size, void* d_ws, size_t ws_size,
                              hipStream_t stream) {
  // inputs: s0, s1, x_0, W_pre, gamma, beta_bn, W_op, edge_index, drop_prob, training
  const float* s1    = (const float*)d_in[1];
  const float* x0    = (const float*)d_in[2];
  const float* W_pre = (const float*)d_in[3];
  const float* gamma = (const float*)d_in[4];
  const float* betab = (const float*)d_in[5];
  const float* W_op  = (const float*)d_in[6];
  const int*   ei    = (const int*)d_in[7];
  float* out = (float*)d_out;

  float* h        = (float*)d_ws;                       // 12.8M floats
  float* agg      = h + (size_t)NNODES * HIDDIM;        // 12.8M floats
  float* colsum   = agg + (size_t)NNODES * HIDDIM;      // 256
  float* colsumsq = colsum + HIDDIM;                    // 256
  float* scale    = colsumsq + HIDDIM;                  // 256
  float* shift    = scale + HIDDIM;                     // 256

  hipMemsetAsync(agg, 0, (size_t)NNODES * HIDDIM * sizeof(float), stream);
  hipMemsetAsync(colsum, 0, 2 * HIDDIM * sizeof(float), stream);

  dim3 gg((NNODES + 63) / 64, HIDDIM / 64);
  gemm_k<0><<<gg, 256, 0, stream>>>(s1, W_pre, h, colsum, colsumsq, NNODES);
  bn_finalize_k<<<1, HIDDIM, 0, stream>>>(colsum, colsumsq, gamma, betab, scale, shift);
  bn_relu_k<<<2048, 256, 0, stream>>>(h, scale, shift);
  scatter_k<<<NEDGES / 4, 256, 0, stream>>>(h, ei, agg);
  support_k<<<2048, 256, 0, stream>>>(h, agg, x0);
  gemm_k<1><<<gg, 256, 0, stream>>>(agg, W_op, out, nullptr, nullptr, NNODES);
}

// Round 3
// 626.262 us; speedup vs baseline: 4.8269x; 4.8269x over previous
//
#include <hip/hip_runtime.h>

#define NNODES 50000
#define NEDGES 800000
#define HIDDIM 256

constexpr float kAlpha = 0.1f;          // initial-residual weight
constexpr float kBnEps = 1e-5f;
constexpr float kBeta  = 0.40546510810816438198f;   // log(1.5)

// ---------------------------------------------------------------------------
// GEMM: C = A[nrows,256] @ B[256,256]  (64x64 tile, 4x4 microtile, fp32)
// MODE 0: also accumulate per-column sum / sumsq (for BatchNorm)
// MODE 1: GCNII epilogue: C = relu((1-beta)*A + beta*(A@B))
// ---------------------------------------------------------------------------
template<int MODE>
__global__ __launch_bounds__(256) void gemm_k(const float* __restrict__ A,
                                              const float* __restrict__ B,
                                              float* __restrict__ C,
                                              float* __restrict__ colsum,
                                              float* __restrict__ colsumsq,
                                              int nrows) {
  __shared__ float As[128][64];        // A-tile, transposed: As[k][row]  (32 KB)
  __shared__ float red[2][16][64];     // column-stat reduction (MODE 0), 8 KB

  const int t  = threadIdx.x;
  const int tx = t & 15;               // column group (4 cols each)
  const int ty = t >> 4;               // row group (4 rows each), 0..15
  const long long row0 = (long long)blockIdx.x * 64;
  const int col0 = blockIdx.y * 64;

  float acc[4][4];
#pragma unroll
  for (int i = 0; i < 4; ++i)
#pragma unroll
    for (int j = 0; j < 4; ++j) acc[i][j] = 0.f;

  const int sr = t >> 2;               // staging row 0..63
  const int sk = (t & 3) * 4;          // staging k-offset
  const bool srow_ok = (row0 + sr) < nrows;
  const float* Arow = A + (row0 + sr) * HIDDIM;

  for (int half = 0; half < 2; ++half) {
    if (half) __syncthreads();
#pragma unroll
    for (int kb = 0; kb < 128; kb += 16) {
      float4 v = make_float4(0.f, 0.f, 0.f, 0.f);
      if (srow_ok) v = *(const float4*)(Arow + half * 128 + kb + sk);
      As[kb + sk + 0][sr] = v.x;
      As[kb + sk + 1][sr] = v.y;
      As[kb + sk + 2][sr] = v.z;
      As[kb + sk + 3][sr] = v.w;
    }
    __syncthreads();

    const float* Bp = B + (half * 128) * HIDDIM + col0 + tx * 4;
#pragma unroll 4
    for (int k = 0; k < 128; ++k) {
      float4 a = *(const float4*)&As[k][ty * 4];
      float4 b = *(const float4*)(Bp + k * HIDDIM);
      acc[0][0] = fmaf(a.x, b.x, acc[0][0]);
      acc[0][1] = fmaf(a.x, b.y, acc[0][1]);
      acc[0][2] = fmaf(a.x, b.z, acc[0][2]);
      acc[0][3] = fmaf(a.x, b.w, acc[0][3]);
      acc[1][0] = fmaf(a.y, b.x, acc[1][0]);
      acc[1][1] = fmaf(a.y, b.y, acc[1][1]);
      acc[1][2] = fmaf(a.y, b.z, acc[1][2]);
      acc[1][3] = fmaf(a.y, b.w, acc[1][3]);
      acc[2][0] = fmaf(a.z, b.x, acc[2][0]);
      acc[2][1] = fmaf(a.z, b.y, acc[2][1]);
      acc[2][2] = fmaf(a.z, b.z, acc[2][2]);
      acc[2][3] = fmaf(a.z, b.w, acc[2][3]);
      acc[3][0] = fmaf(a.w, b.x, acc[3][0]);
      acc[3][1] = fmaf(a.w, b.y, acc[3][1]);
      acc[3][2] = fmaf(a.w, b.z, acc[3][2]);
      acc[3][3] = fmaf(a.w, b.w, acc[3][3]);
    }
  }

#pragma unroll
  for (int i = 0; i < 4; ++i) {
    long long r = row0 + ty * 4 + i;
    if (r < nrows) {
      float4 o;
      if (MODE == 0) {
        o = make_float4(acc[i][0], acc[i][1], acc[i][2], acc[i][3]);
      } else {
        float4 s = *(const float4*)(A + r * HIDDIM + col0 + tx * 4);
        o.x = fmaxf((1.f - kBeta) * s.x + kBeta * acc[i][0], 0.f);
        o.y = fmaxf((1.f - kBeta) * s.y + kBeta * acc[i][1], 0.f);
        o.z = fmaxf((1.f - kBeta) * s.z + kBeta * acc[i][2], 0.f);
        o.w = fmaxf((1.f - kBeta) * s.w + kBeta * acc[i][3], 0.f);
      }
      *(float4*)(C + r * HIDDIM + col0 + tx * 4) = o;
    }
  }

  if (MODE == 0) {
#pragma unroll
    for (int j = 0; j < 4; ++j) {
      float s  = acc[0][j] + acc[1][j] + acc[2][j] + acc[3][j];
      float s2 = acc[0][j] * acc[0][j] + acc[1][j] * acc[1][j] +
                 acc[2][j] * acc[2][j] + acc[3][j] * acc[3][j];
      red[0][ty][tx * 4 + j] = s;
      red[1][ty][tx * 4 + j] = s2;
    }
    __syncthreads();
    if (t < 64) {
      float ssum = 0.f, s2sum = 0.f;
#pragma unroll
      for (int g = 0; g < 16; ++g) {
        ssum  += red[0][g][t];
        s2sum += red[1][g][t];
      }
      atomicAdd(&colsum[col0 + t], ssum);
      atomicAdd(&colsumsq[col0 + t], s2sum);
    }
  }
}

// ---------------------------------------------------------------------------
__global__ __launch_bounds__(256) void bn_finalize_k(const float* __restrict__ colsum,
                                                     const float* __restrict__ colsumsq,
                                                     const float* __restrict__ gamma,
                                                     const float* __restrict__ beta_bn,
                                                     float* __restrict__ scale,
                                                     float* __restrict__ shift) {
  int j = threadIdx.x;
  float inv_n = 1.0f / (float)NNODES;
  float mu  = colsum[j] * inv_n;
  float var = colsumsq[j] * inv_n - mu * mu;
  float rstd = rsqrtf(var + kBnEps);
  float sc = gamma[j] * rstd;
  scale[j] = sc;
  shift[j] = beta_bn[j] - mu * sc;
}

// ---------------------------------------------------------------------------
__global__ __launch_bounds__(256) void bn_relu_k(float* __restrict__ h,
                                                 const float* __restrict__ scale,
                                                 const float* __restrict__ shift) {
  const int n4 = NNODES * HIDDIM / 4;
  int stride = gridDim.x * blockDim.x;
  for (int i = blockIdx.x * blockDim.x + threadIdx.x; i < n4; i += stride) {
    float4 v = ((const float4*)h)[i];
    int c = (i << 2) & (HIDDIM - 1);
    v.x = fmaxf(fmaf(v.x, scale[c + 0], shift[c + 0]), 0.f);
    v.y = fmaxf(fmaf(v.y, scale[c + 1], shift[c + 1]), 0.f);
    v.z = fmaxf(fmaf(v.z, scale[c + 2], shift[c + 2]), 0.f);
    v.w = fmaxf(fmaf(v.w, scale[c + 3], shift[c + 3]), 0.f);
    ((float4*)h)[i] = v;
  }
}

// ---------------------------------------------------------------------------
// CSR build: degree histogram -> exclusive scan -> bucket src ids
// ---------------------------------------------------------------------------
__global__ __launch_bounds__(256) void hist_k(const int* __restrict__ ei,
                                              int* __restrict__ deg) {
  int stride = gridDim.x * blockDim.x;
  for (int e = blockIdx.x * blockDim.x + threadIdx.x; e < NEDGES; e += stride)
    atomicAdd(&deg[ei[NEDGES + e]], 1);
}

__global__ __launch_bounds__(1024) void scan_k(const int* __restrict__ deg,
                                               int* __restrict__ rowptr) {
  __shared__ int part[1024];
  const int t = threadIdx.x;
  const int PER = (NNODES + 1023) / 1024;   // 49
  const int base = t * PER;
  int sum = 0;
  for (int i = 0; i < PER; ++i) {
    int idx = base + i;
    if (idx < NNODES) sum += deg[idx];
  }
  part[t] = sum;
  __syncthreads();
  // Hillis-Steele inclusive scan over 1024 partials
  for (int off = 1; off < 1024; off <<= 1) {
    int v = (t >= off) ? part[t - off] : 0;
    __syncthreads();
    part[t] += v;
    __syncthreads();
  }
  int run = part[t] - sum;                  // exclusive prefix
  for (int i = 0; i < PER; ++i) {
    int idx = base + i;
    if (idx < NNODES) { rowptr[idx] = run; run += deg[idx]; }
  }
  if (t == 1023) rowptr[NNODES] = part[1023];
}

__global__ __launch_bounds__(256) void fill_k(const int* __restrict__ ei,
                                              const int* __restrict__ rowptr,
                                              int* __restrict__ cursor,
                                              int* __restrict__ esrc) {
  int stride = gridDim.x * blockDim.x;
  for (int e = blockIdx.x * blockDim.x + threadIdx.x; e < NEDGES; e += stride) {
    int d = ei[NEDGES + e];
    int pos = atomicAdd(&cursor[d], 1);
    esrc[rowptr[d] + pos] = ei[e];
  }
}

// ---------------------------------------------------------------------------
// Gather-sum per destination node (one 64-lane wave per node), fused with
// the GCNII support mix:  supp[d] = 0.9*(h[d] + sum_{s in N(d)} h[s]) + 0.1*x0[d]
// ---------------------------------------------------------------------------
__global__ __launch_bounds__(256) void agg_support_k(const float* __restrict__ h,
                                                     const int* __restrict__ rowptr,
                                                     const int* __restrict__ esrc,
                                                     const float* __restrict__ x0,
                                                     float* __restrict__ supp) {
  const int lane = threadIdx.x & 63;
  const int d = (blockIdx.x * blockDim.x + threadIdx.x) >> 6;
  if (d >= NNODES) return;
  const int beg = rowptr[d];
  const int end = rowptr[d + 1];
  const int off = lane * 4;

  float4 acc = make_float4(0.f, 0.f, 0.f, 0.f);
  int e = beg;
  for (; e + 1 < end; e += 2) {
    int s0 = esrc[e];
    int s1 = esrc[e + 1];
    float4 v0 = *(const float4*)(h + (long long)s0 * HIDDIM + off);
    float4 v1 = *(const float4*)(h + (long long)s1 * HIDDIM + off);
    acc.x += v0.x; acc.y += v0.y; acc.z += v0.z; acc.w += v0.w;
    acc.x += v1.x; acc.y += v1.y; acc.z += v1.z; acc.w += v1.w;
  }
  if (e < end) {
    int s0 = esrc[e];
    float4 v0 = *(const float4*)(h + (long long)s0 * HIDDIM + off);
    acc.x += v0.x; acc.y += v0.y; acc.z += v0.z; acc.w += v0.w;
  }

  float4 hh = *(const float4*)(h  + (long long)d * HIDDIM + off);
  float4 xx = *(const float4*)(x0 + (long long)d * HIDDIM + off);
  float4 o;
  o.x = (1.f - kAlpha) * (hh.x + acc.x) + kAlpha * xx.x;
  o.y = (1.f - kAlpha) * (hh.y + acc.y) + kAlpha * xx.y;
  o.z = (1.f - kAlpha) * (hh.z + acc.z) + kAlpha * xx.z;
  o.w = (1.f - kAlpha) * (hh.w + acc.w) + kAlpha * xx.w;
  *(float4*)(supp + (long long)d * HIDDIM + off) = o;
}

// ---------------------------------------------------------------------------
extern "C" void kernel_launch(void* const* d_in, const int* in_sizes, int n_in,
                              void* d_out, int out_size, void* d_ws, size_t ws_size,
                              hipStream_t stream) {
  // inputs: s0, s1, x_0, W_pre, gamma, beta_bn, W_op, edge_index, drop_prob, training
  const float* s1    = (const float*)d_in[1];
  const float* x0    = (const float*)d_in[2];
  const float* W_pre = (const float*)d_in[3];
  const float* gamma = (const float*)d_in[4];
  const float* betab = (const float*)d_in[5];
  const float* W_op  = (const float*)d_in[6];
  const int*   ei    = (const int*)d_in[7];
  float* out = (float*)d_out;

  // workspace layout
  float* h        = (float*)d_ws;                       // 12.8M floats (51.2 MB)
  float* supp     = h + (size_t)NNODES * HIDDIM;        // 12.8M floats (51.2 MB)
  float* colsum   = supp + (size_t)NNODES * HIDDIM;     // 256
  float* colsumsq = colsum + HIDDIM;                    // 256
  float* scale    = colsumsq + HIDDIM;                  // 256
  float* shift    = scale + HIDDIM;                     // 256
  int*   deg      = (int*)(shift + HIDDIM);             // 50000
  int*   cursor   = deg + NNODES;                       // 50000
  int*   rowptr   = cursor + NNODES;                    // 50001
  int*   esrc     = rowptr + (NNODES + 1);              // 800000

  hipMemsetAsync(colsum, 0, 2 * HIDDIM * sizeof(float), stream);
  hipMemsetAsync(deg, 0, 2 * NNODES * sizeof(int), stream);   // deg + cursor

  dim3 gg((NNODES + 63) / 64, HIDDIM / 64);
  gemm_k<0><<<gg, 256, 0, stream>>>(s1, W_pre, h, colsum, colsumsq, NNODES);
  bn_finalize_k<<<1, HIDDIM, 0, stream>>>(colsum, colsumsq, gamma, betab, scale, shift);
  bn_relu_k<<<2048, 256, 0, stream>>>(h, scale, shift);
  hist_k<<<1024, 256, 0, stream>>>(ei, deg);
  scan_k<<<1, 1024, 0, stream>>>(deg, rowptr);
  fill_k<<<1024, 256, 0, stream>>>(ei, rowptr, cursor, esrc);
  agg_support_k<<<(NNODES * 64 + 255) / 256, 256, 0, stream>>>(h, rowptr, esrc, x0, supp);
  gemm_k<1><<<gg, 256, 0, stream>>>(supp, W_op, out, nullptr, nullptr, NNODES);
}

// Round 4
// 413.510 us; speedup vs baseline: 7.3103x; 1.5145x over previous
//
#include <hip/hip_runtime.h>

#define NNODES 50000
#define NEDGES 800000
#define HIDDIM 256

constexpr float kAlpha = 0.1f;
constexpr float kBnEps = 1e-5f;
constexpr float kBeta  = 0.40546510810816438198f;   // log(1.5)

typedef __attribute__((ext_vector_type(8))) short  bf16x8;   // 8 bf16 in 4 VGPRs
typedef __attribute__((ext_vector_type(4))) float  f32x4;

static __device__ __forceinline__ unsigned short f2bf(float f) {
  unsigned u = __float_as_uint(f);
  u = (u + 0x7FFFu + ((u >> 16) & 1u)) >> 16;      // RTNE
  return (unsigned short)u;
}
static __device__ __forceinline__ float bf2f(unsigned short h) {
  return __uint_as_float(((unsigned)h) << 16);
}

// ---------------------------------------------------------------------------
// fp32 -> bf16 streaming convert (float4 -> ushort4)
// ---------------------------------------------------------------------------
__global__ __launch_bounds__(256) void conv_bf_k(const float* __restrict__ src,
                                                 unsigned short* __restrict__ dst,
                                                 int n4) {
  int stride = gridDim.x * blockDim.x;
  for (int i = blockIdx.x * blockDim.x + threadIdx.x; i < n4; i += stride) {
    float4 v = ((const float4*)src)[i];
    ushort4 o;
    o.x = f2bf(v.x); o.y = f2bf(v.y); o.z = f2bf(v.z); o.w = f2bf(v.w);
    ((ushort4*)dst)[i] = o;
  }
}

// W[k][n] fp32 -> Wt[n][k] bf16 (transpose + convert; tiny)
__global__ __launch_bounds__(256) void conv_wt_k(const float* __restrict__ W,
                                                 unsigned short* __restrict__ Wt) {
  int n = blockIdx.x, k = threadIdx.x;
  Wt[n * 256 + k] = f2bf(W[k * 256 + n]);
}

// ---------------------------------------------------------------------------
// bf16 MFMA GEMM: C = A[M,256] @ B[256,256], Bt given transposed [n][k].
// 128x128 tile, BK=64, 4 waves (2x2), 16x16x32 MFMA, XOR-swizzled LDS.
// MODE 0: C fp32 + per-column sum/sumsq atomics (for BatchNorm)
// MODE 1: C = relu((1-beta)*S + beta*(A@B)), S = supp bf16
// ---------------------------------------------------------------------------
template<int MODE>
__global__ __launch_bounds__(256) void gemm_bf16_k(
    const unsigned short* __restrict__ A,    // [M][256] bf16
    const unsigned short* __restrict__ Bt,   // [256][256] bf16, Bt[n][k]
    float* __restrict__ C,                   // [M][256] fp32
    const unsigned short* __restrict__ S,    // MODE1: supp bf16
    float* __restrict__ colsum,
    float* __restrict__ colsumsq,
    int M) {
  __shared__ unsigned short Al[128 * 64];    // 16 KB, row stride 128 B, XOR-swizzled
  __shared__ unsigned short Bl[128 * 64];    // 16 KB
  __shared__ float cs[4][64], cq[4][64];     // MODE0 column-stat reduction

  const int t    = threadIdx.x;
  const int lane = t & 63;
  const int wid  = t >> 6;
  const int wr   = wid >> 1;                 // wave row (0/1): rows wr*64..+63
  const int wc   = wid & 1;                  // wave col (0/1): cols wc*64..+63
  const int row0    = blockIdx.x * 128;
  const int colbase = blockIdx.y * 128;

  f32x4 acc[4][4] = {};

  // staging: thread -> (tile row, k-half)
  const int srow = t & 127;
  const int sseg = t >> 7;                   // 0: k 0..31, 1: k 32..63
  const int arow = row0 + srow;
  const bool aok = arow < M;
  const int swz  = (srow & 7) << 4;

  for (int ks = 0; ks < 4; ++ks) {
    if (ks) __syncthreads();
    const int k0 = ks * 64;
    // ---- stage A (zero-pad OOB rows) ----
    {
      const unsigned short* src = A + (size_t)arow * 256 + k0 + sseg * 32;
#pragma unroll
      for (int c = 0; c < 4; ++c) {
        int byteoff = srow * 128 + ((sseg * 64 + c * 16) ^ swz);
        bf16x8 v = {};
        if (aok) v = *(const bf16x8*)(src + c * 8);
        *(bf16x8*)((char*)Al + byteoff) = v;
      }
    }
    // ---- stage B ----
    {
      const unsigned short* src = Bt + (size_t)(colbase + srow) * 256 + k0 + sseg * 32;
#pragma unroll
      for (int c = 0; c < 4; ++c) {
        int byteoff = srow * 128 + ((sseg * 64 + c * 16) ^ swz);
        *(bf16x8*)((char*)Bl + byteoff) = *(const bf16x8*)(src + c * 8);
      }
    }
    __syncthreads();
    // ---- compute: 2 k-slices x 16 MFMA ----
#pragma unroll
    for (int kk = 0; kk < 2; ++kk) {
      const int koff = kk * 64 + ((lane >> 4) * 16);
      bf16x8 af[4], bfr[4];
#pragma unroll
      for (int m = 0; m < 4; ++m) {
        int row = wr * 64 + m * 16 + (lane & 15);
        af[m] = *(const bf16x8*)((char*)Al + row * 128 + (koff ^ ((row & 7) << 4)));
      }
#pragma unroll
      for (int n = 0; n < 4; ++n) {
        int nr = wc * 64 + n * 16 + (lane & 15);
        bfr[n] = *(const bf16x8*)((char*)Bl + nr * 128 + (koff ^ ((nr & 7) << 4)));
      }
#pragma unroll
      for (int m = 0; m < 4; ++m)
#pragma unroll
        for (int n = 0; n < 4; ++n)
          acc[m][n] = __builtin_amdgcn_mfma_f32_16x16x32_bf16(af[m], bfr[n], acc[m][n], 0, 0, 0);
    }
  }

  // ---- MODE 0: column sum / sumsq (OOB rows contributed exact zeros) ----
  if (MODE == 0) {
#pragma unroll
    for (int n = 0; n < 4; ++n) {
      float s = 0.f, q = 0.f;
#pragma unroll
      for (int m = 0; m < 4; ++m)
#pragma unroll
        for (int r = 0; r < 4; ++r) {
          float v = acc[m][n][r];
          s += v; q += v * v;
        }
      s += __shfl_xor(s, 16); s += __shfl_xor(s, 32);
      q += __shfl_xor(q, 16); q += __shfl_xor(q, 32);
      if (lane < 16) { cs[wid][n * 16 + lane] = s; cq[wid][n * 16 + lane] = q; }
    }
    __syncthreads();
    if (t < 128) {
      int sel = t >> 6, lc = t & 63;
      atomicAdd(&colsum[colbase + t],   cs[sel][lc] + cs[2 + sel][lc]);
      atomicAdd(&colsumsq[colbase + t], cq[sel][lc] + cq[2 + sel][lc]);
    }
  }

  // ---- store (C/D layout: col=lane&15, row=(lane>>4)*4+r) ----
#pragma unroll
  for (int m = 0; m < 4; ++m) {
    int rbase = row0 + wr * 64 + m * 16 + (lane >> 4) * 4;
#pragma unroll
    for (int r = 0; r < 4; ++r) {
      int row = rbase + r;
      if (row < M) {
#pragma unroll
        for (int n = 0; n < 4; ++n) {
          int col = colbase + wc * 64 + n * 16 + (lane & 15);
          float v = acc[m][n][r];
          if (MODE == 1) {
            float s = bf2f(S[(size_t)row * 256 + col]);
            v = fmaxf((1.f - kBeta) * s + kBeta * v, 0.f);
          }
          C[(size_t)row * 256 + col] = v;
        }
      }
    }
  }
}

// ---------------------------------------------------------------------------
__global__ __launch_bounds__(256) void bn_finalize_k(const float* __restrict__ colsum,
                                                     const float* __restrict__ colsumsq,
                                                     const float* __restrict__ gamma,
                                                     const float* __restrict__ beta_bn,
                                                     float* __restrict__ scale,
                                                     float* __restrict__ shift) {
  int j = threadIdx.x;
  float inv_n = 1.0f / (float)NNODES;
  float mu  = colsum[j] * inv_n;
  float var = colsumsq[j] * inv_n - mu * mu;
  float rstd = rsqrtf(var + kBnEps);
  float sc = gamma[j] * rstd;
  scale[j] = sc;
  shift[j] = beta_bn[j] - mu * sc;
}

// ---------------------------------------------------------------------------
__global__ __launch_bounds__(256) void bn_relu_k(float* __restrict__ h,
                                                 const float* __restrict__ scale,
                                                 const float* __restrict__ shift) {
  const int n4 = NNODES * HIDDIM / 4;
  int stride = gridDim.x * blockDim.x;
  for (int i = blockIdx.x * blockDim.x + threadIdx.x; i < n4; i += stride) {
    float4 v = ((const float4*)h)[i];
    int c = (i << 2) & (HIDDIM - 1);
    v.x = fmaxf(fmaf(v.x, scale[c + 0], shift[c + 0]), 0.f);
    v.y = fmaxf(fmaf(v.y, scale[c + 1], shift[c + 1]), 0.f);
    v.z = fmaxf(fmaf(v.z, scale[c + 2], shift[c + 2]), 0.f);
    v.w = fmaxf(fmaf(v.w, scale[c + 3], shift[c + 3]), 0.f);
    ((float4*)h)[i] = v;
  }
}

// ---------------------------------------------------------------------------
// CSR build: degree histogram -> exclusive scan -> bucket src ids
// ---------------------------------------------------------------------------
__global__ __launch_bounds__(256) void hist_k(const int* __restrict__ ei,
                                              int* __restrict__ deg) {
  int stride = gridDim.x * blockDim.x;
  for (int e = blockIdx.x * blockDim.x + threadIdx.x; e < NEDGES; e += stride)
    atomicAdd(&deg[ei[NEDGES + e]], 1);
}

__global__ __launch_bounds__(1024) void scan_k(const int* __restrict__ deg,
                                               int* __restrict__ rowptr) {
  __shared__ int part[1024];
  const int t = threadIdx.x;
  const int PER = (NNODES + 1023) / 1024;
  const int base = t * PER;
  int sum = 0;
  for (int i = 0; i < PER; ++i) {
    int idx = base + i;
    if (idx < NNODES) sum += deg[idx];
  }
  part[t] = sum;
  __syncthreads();
  for (int off = 1; off < 1024; off <<= 1) {
    int v = (t >= off) ? part[t - off] : 0;
    __syncthreads();
    part[t] += v;
    __syncthreads();
  }
  int run = part[t] - sum;
  for (int i = 0; i < PER; ++i) {
    int idx = base + i;
    if (idx < NNODES) { rowptr[idx] = run; run += deg[idx]; }
  }
  if (t == 1023) rowptr[NNODES] = part[1023];
}

__global__ __launch_bounds__(256) void fill_k(const int* __restrict__ ei,
                                              const int* __restrict__ rowptr,
                                              int* __restrict__ cursor,
                                              int* __restrict__ esrc) {
  int stride = gridDim.x * blockDim.x;
  for (int e = blockIdx.x * blockDim.x + threadIdx.x; e < NEDGES; e += stride) {
    int d = ei[NEDGES + e];
    int pos = atomicAdd(&cursor[d], 1);
    esrc[rowptr[d] + pos] = ei[e];
  }
}

// ---------------------------------------------------------------------------
// Gather-sum per destination node (64-lane wave), fused GCNII support mix,
// output written as bf16 (feeds GEMM2's A and its residual read).
// ---------------------------------------------------------------------------
__global__ __launch_bounds__(256) void agg_support_k(const float* __restrict__ h,
                                                     const int* __restrict__ rowptr,
                                                     const int* __restrict__ esrc,
                                                     const float* __restrict__ x0,
                                                     unsigned short* __restrict__ supp_bf) {
  const int lane = threadIdx.x & 63;
  const int d = (blockIdx.x * blockDim.x + threadIdx.x) >> 6;
  if (d >= NNODES) return;
  const int beg = rowptr[d];
  const int end = rowptr[d + 1];
  const int off = lane * 4;

  float4 acc = make_float4(0.f, 0.f, 0.f, 0.f);
  int e = beg;
  for (; e + 1 < end; e += 2) {
    int s0 = esrc[e];
    int s1 = esrc[e + 1];
    float4 v0 = *(const float4*)(h + (long long)s0 * HIDDIM + off);
    float4 v1 = *(const float4*)(h + (long long)s1 * HIDDIM + off);
    acc.x += v0.x; acc.y += v0.y; acc.z += v0.z; acc.w += v0.w;
    acc.x += v1.x; acc.y += v1.y; acc.z += v1.z; acc.w += v1.w;
  }
  if (e < end) {
    int s0 = esrc[e];
    float4 v0 = *(const float4*)(h + (long long)s0 * HIDDIM + off);
    acc.x += v0.x; acc.y += v0.y; acc.z += v0.z; acc.w += v0.w;
  }

  float4 hh = *(const float4*)(h  + (long long)d * HIDDIM + off);
  float4 xx = *(const float4*)(x0 + (long long)d * HIDDIM + off);
  ushort4 o;
  o.x = f2bf((1.f - kAlpha) * (hh.x + acc.x) + kAlpha * xx.x);
  o.y = f2bf((1.f - kAlpha) * (hh.y + acc.y) + kAlpha * xx.y);
  o.z = f2bf((1.f - kAlpha) * (hh.z + acc.z) + kAlpha * xx.z);
  o.w = f2bf((1.f - kAlpha) * (hh.w + acc.w) + kAlpha * xx.w);
  *(ushort4*)(supp_bf + (long long)d * HIDDIM + off) = o;
}

// ---------------------------------------------------------------------------
extern "C" void kernel_launch(void* const* d_in, const int* in_sizes, int n_in,
                              void* d_out, int out_size, void* d_ws, size_t ws_size,
                              hipStream_t stream) {
  // inputs: s0, s1, x_0, W_pre, gamma, beta_bn, W_op, edge_index, drop_prob, training
  const float* s1    = (const float*)d_in[1];
  const float* x0    = (const float*)d_in[2];
  const float* W_pre = (const float*)d_in[3];
  const float* gamma = (const float*)d_in[4];
  const float* betab = (const float*)d_in[5];
  const float* W_op  = (const float*)d_in[6];
  const int*   ei    = (const int*)d_in[7];
  float* out = (float*)d_out;

  const size_t NH = (size_t)NNODES * HIDDIM;      // 12.8M
  float* h        = (float*)d_ws;                 // 51.2 MB
  float* colsum   = h + NH;                       // 256
  float* colsumsq = colsum + HIDDIM;
  float* scale    = colsumsq + HIDDIM;
  float* shift    = scale + HIDDIM;
  unsigned short* abf    = (unsigned short*)(shift + HIDDIM);  // 25.6 MB (s1_bf16, later supp_bf16)
  unsigned short* wpre_t = abf + NH;              // 128 KB
  unsigned short* wop_t  = wpre_t + 65536;        // 128 KB
  int* deg    = (int*)(wop_t + 65536);            // 50000
  int* cursor = deg + NNODES;                     // 50000
  int* rowptr = cursor + NNODES;                  // 50001
  int* esrc   = rowptr + (NNODES + 1);            // 800000

  hipMemsetAsync(colsum, 0, 2 * HIDDIM * sizeof(float), stream);
  hipMemsetAsync(deg, 0, 2 * NNODES * sizeof(int), stream);    // deg + cursor

  conv_wt_k<<<256, 256, 0, stream>>>(W_pre, wpre_t);
  conv_wt_k<<<256, 256, 0, stream>>>(W_op, wop_t);
  conv_bf_k<<<2048, 256, 0, stream>>>(s1, abf, (int)(NH / 4));

  dim3 gg((NNODES + 127) / 128, 2);
  gemm_bf16_k<0><<<gg, 256, 0, stream>>>(abf, wpre_t, h, nullptr, colsum, colsumsq, NNODES);
  bn_finalize_k<<<1, HIDDIM, 0, stream>>>(colsum, colsumsq, gamma, betab, scale, shift);
  bn_relu_k<<<2048, 256, 0, stream>>>(h, scale, shift);

  hist_k<<<1024, 256, 0, stream>>>(ei, deg);
  scan_k<<<1, 1024, 0, stream>>>(deg, rowptr);
  fill_k<<<1024, 256, 0, stream>>>(ei, rowptr, cursor, esrc);
  agg_support_k<<<(NNODES * 64 + 255) / 256, 256, 0, stream>>>(h, rowptr, esrc, x0, abf);

  gemm_bf16_k<1><<<gg, 256, 0, stream>>>(abf, wop_t, out, abf, nullptr, nullptr, NNODES);
}

// Round 5
// 343.476 us; speedup vs baseline: 8.8008x; 1.2039x over previous
//
#include <hip/hip_runtime.h>

#define NNODES 50000
#define NEDGES 800000
#define HIDDIM 256

constexpr float kAlpha = 0.1f;
constexpr float kBnEps = 1e-5f;
constexpr float kBeta  = 0.40546510810816438198f;   // log(1.5)

typedef __attribute__((ext_vector_type(8))) short  bf16x8;   // 8 bf16 in 4 VGPRs
typedef __attribute__((ext_vector_type(4))) float  f32x4;

static __device__ __forceinline__ unsigned short f2bf(float f) {
  unsigned u = __float_as_uint(f);
  u = (u + 0x7FFFu + ((u >> 16) & 1u)) >> 16;      // RTNE
  return (unsigned short)u;
}
static __device__ __forceinline__ float bf2f(unsigned short h) {
  return __uint_as_float(((unsigned)h) << 16);
}

// ---------------------------------------------------------------------------
// fp32 -> bf16 streaming convert
// ---------------------------------------------------------------------------
__global__ __launch_bounds__(256) void conv_bf_k(const float* __restrict__ src,
                                                 unsigned short* __restrict__ dst,
                                                 int n4) {
  int stride = gridDim.x * blockDim.x;
  for (int i = blockIdx.x * blockDim.x + threadIdx.x; i < n4; i += stride) {
    float4 v = ((const float4*)src)[i];
    ushort4 o;
    o.x = f2bf(v.x); o.y = f2bf(v.y); o.z = f2bf(v.z); o.w = f2bf(v.w);
    ((ushort4*)dst)[i] = o;
  }
}

// W[k][n] fp32 -> Wt[n][k] bf16 (transpose + convert; tiny)
__global__ __launch_bounds__(256) void conv_wt_k(const float* __restrict__ W,
                                                 unsigned short* __restrict__ Wt) {
  int n = blockIdx.x, k = threadIdx.x;
  Wt[n * 256 + k] = f2bf(W[k * 256 + n]);
}

// ---------------------------------------------------------------------------
// bf16 MFMA GEMM: C = A[M,256] @ B[256,256], Bt transposed [n][k].
// 128x256 tile (single column tile), BK=64, 4 waves (2x2, each 64r x 128c).
// MODE 0: C bf16 + per-column sum/sumsq atomics (BatchNorm stats)
// MODE 1: C fp32 = relu((1-beta)*S + beta*(A@B)), S = supp bf16
// ---------------------------------------------------------------------------
template<int MODE>
__global__ __launch_bounds__(256) void gemm_bf16_k(
    const unsigned short* __restrict__ A,    // [M][256] bf16
    const unsigned short* __restrict__ Bt,   // [256][256] bf16, Bt[n][k]
    void* __restrict__ Cout,                 // MODE0: bf16; MODE1: float
    const unsigned short* __restrict__ S,    // MODE1: residual bf16
    float* __restrict__ colsum,
    float* __restrict__ colsumsq,
    int M) {
  __shared__ unsigned short Al[128 * 64];    // 16 KB, row stride 128 B, XOR-swizzled
  __shared__ unsigned short Bl[256 * 64];    // 32 KB
  __shared__ float cs[4][128], cq[4][128];   // MODE0 column-stat reduction (8 KB)

  const int t    = threadIdx.x;
  const int lane = t & 63;
  const int wid  = t >> 6;
  const int wr   = wid >> 1;                 // wave row (0/1): rows wr*64..+63
  const int wc   = wid & 1;                  // wave col (0/1): cols wc*128..+127
  const int row0 = blockIdx.x * 128;

  f32x4 acc[4][8] = {};

  const int srow = t & 127;                  // A staging row
  const int sseg = t >> 7;                   // A staging k-half (32 k each)
  const int arow = row0 + srow;
  const bool aok = arow < M;
  const int swzA = (srow & 7) << 4;
  const int swzB = (t & 7) << 4;

  for (int ks = 0; ks < 4; ++ks) {
    if (ks) __syncthreads();
    const int k0 = ks * 64;
    // ---- stage A (zero-pad OOB rows): thread -> half-row, 4x16B chunks ----
    {
      const unsigned short* src = A + (size_t)arow * 256 + k0 + sseg * 32;
#pragma unroll
      for (int c = 0; c < 4; ++c) {
        int byteoff = srow * 128 + ((sseg * 64 + c * 16) ^ swzA);
        bf16x8 v = {};
        if (aok) v = *(const bf16x8*)(src + c * 8);
        *(bf16x8*)((char*)Al + byteoff) = v;
      }
    }
    // ---- stage B: thread -> full row t (256 rows), 8x16B chunks ----
    {
      const unsigned short* src = Bt + (size_t)t * 256 + k0;
#pragma unroll
      for (int c = 0; c < 8; ++c) {
        int byteoff = t * 128 + ((c * 16) ^ swzB);
        *(bf16x8*)((char*)Bl + byteoff) = *(const bf16x8*)(src + c * 8);
      }
    }
    __syncthreads();
    // ---- compute: 2 k-slices x 32 MFMA ----
#pragma unroll
    for (int kk = 0; kk < 2; ++kk) {
      const int koff = kk * 64 + ((lane >> 4) * 16);   // byte offset in row
      bf16x8 af[4], bfr[8];
#pragma unroll
      for (int m = 0; m < 4; ++m) {
        int row = wr * 64 + m * 16 + (lane & 15);
        af[m] = *(const bf16x8*)((char*)Al + row * 128 + (koff ^ ((row & 7) << 4)));
      }
#pragma unroll
      for (int n = 0; n < 8; ++n) {
        int nr = wc * 128 + n * 16 + (lane & 15);
        bfr[n] = *(const bf16x8*)((char*)Bl + nr * 128 + (koff ^ ((nr & 7) << 4)));
      }
#pragma unroll
      for (int m = 0; m < 4; ++m)
#pragma unroll
        for (int n = 0; n < 8; ++n)
          acc[m][n] = __builtin_amdgcn_mfma_f32_16x16x32_bf16(af[m], bfr[n], acc[m][n], 0, 0, 0);
    }
  }

  // ---- MODE 0: column sum / sumsq (OOB rows contributed exact zeros) ----
  if (MODE == 0) {
#pragma unroll
    for (int n = 0; n < 8; ++n) {
      float s = 0.f, q = 0.f;
#pragma unroll
      for (int m = 0; m < 4; ++m)
#pragma unroll
        for (int r = 0; r < 4; ++r) {
          float v = acc[m][n][r];
          s += v; q += v * v;
        }
      s += __shfl_xor(s, 16); s += __shfl_xor(s, 32);
      q += __shfl_xor(q, 16); q += __shfl_xor(q, 32);
      if (lane < 16) { cs[wid][n * 16 + lane] = s; cq[wid][n * 16 + lane] = q; }
    }
    __syncthreads();
    {
      int wcg = t >> 7;                      // column half (0/1)
      int lc  = t & 127;
      atomicAdd(&colsum[t],   cs[wcg][lc] + cs[wcg + 2][lc]);
      atomicAdd(&colsumsq[t], cq[wcg][lc] + cq[wcg + 2][lc]);
    }
  }

  // ---- store (C/D layout: col=lane&15, row=(lane>>4)*4+r) ----
#pragma unroll
  for (int m = 0; m < 4; ++m) {
    int rbase = row0 + wr * 64 + m * 16 + (lane >> 4) * 4;
#pragma unroll
    for (int r = 0; r < 4; ++r) {
      int row = rbase + r;
      if (row < M) {
#pragma unroll
        for (int n = 0; n < 8; ++n) {
          int col = wc * 128 + n * 16 + (lane & 15);
          float v = acc[m][n][r];
          if (MODE == 0) {
            ((unsigned short*)Cout)[(size_t)row * 256 + col] = f2bf(v);
          } else {
            float s = bf2f(S[(size_t)row * 256 + col]);
            ((float*)Cout)[(size_t)row * 256 + col] =
                fmaxf((1.f - kBeta) * s + kBeta * v, 0.f);
          }
        }
      }
    }
  }
}

// ---------------------------------------------------------------------------
__global__ __launch_bounds__(256) void bn_finalize_k(const float* __restrict__ colsum,
                                                     const float* __restrict__ colsumsq,
                                                     const float* __restrict__ gamma,
                                                     const float* __restrict__ beta_bn,
                                                     float* __restrict__ scale,
                                                     float* __restrict__ shift) {
  int j = threadIdx.x;
  float inv_n = 1.0f / (float)NNODES;
  float mu  = colsum[j] * inv_n;
  float var = colsumsq[j] * inv_n - mu * mu;
  float rstd = rsqrtf(var + kBnEps);
  float sc = gamma[j] * rstd;
  scale[j] = sc;
  shift[j] = beta_bn[j] - mu * sc;
}

// ---------------------------------------------------------------------------
// In-place BN-apply + ReLU on bf16 h (8 elems / thread / iter)
// ---------------------------------------------------------------------------
__global__ __launch_bounds__(256) void bn_relu_bf_k(unsigned short* __restrict__ h,
                                                    const float* __restrict__ scale,
                                                    const float* __restrict__ shift) {
  const int n8 = NNODES * HIDDIM / 8;
  int stride = gridDim.x * blockDim.x;
  for (int i = blockIdx.x * blockDim.x + threadIdx.x; i < n8; i += stride) {
    bf16x8 v = ((const bf16x8*)h)[i];
    int c0 = (i << 3) & (HIDDIM - 1);
    bf16x8 o;
#pragma unroll
    for (int j = 0; j < 8; ++j) {
      float f = bf2f((unsigned short)v[j]);
      f = fmaxf(fmaf(f, scale[c0 + j], shift[c0 + j]), 0.f);
      o[j] = (short)f2bf(f);
    }
    ((bf16x8*)h)[i] = o;
  }
}

// ---------------------------------------------------------------------------
// CSR build: degree histogram -> exclusive scan -> bucket src ids
// ---------------------------------------------------------------------------
__global__ __launch_bounds__(256) void hist_k(const int* __restrict__ ei,
                                              int* __restrict__ deg) {
  int stride = gridDim.x * blockDim.x;
  for (int e = blockIdx.x * blockDim.x + threadIdx.x; e < NEDGES; e += stride)
    atomicAdd(&deg[ei[NEDGES + e]], 1);
}

__global__ __launch_bounds__(1024) void scan_k(const int* __restrict__ deg,
                                               int* __restrict__ rowptr) {
  __shared__ int part[1024];
  const int t = threadIdx.x;
  const int PER = (NNODES + 1023) / 1024;
  const int base = t * PER;
  int sum = 0;
  for (int i = 0; i < PER; ++i) {
    int idx = base + i;
    if (idx < NNODES) sum += deg[idx];
  }
  part[t] = sum;
  __syncthreads();
  for (int off = 1; off < 1024; off <<= 1) {
    int v = (t >= off) ? part[t - off] : 0;
    __syncthreads();
    part[t] += v;
    __syncthreads();
  }
  int run = part[t] - sum;
  for (int i = 0; i < PER; ++i) {
    int idx = base + i;
    if (idx < NNODES) { rowptr[idx] = run; run += deg[idx]; }
  }
  if (t == 1023) rowptr[NNODES] = part[1023];
}

__global__ __launch_bounds__(256) void fill_k(const int* __restrict__ ei,
                                              const int* __restrict__ rowptr,
                                              int* __restrict__ cursor,
                                              int* __restrict__ esrc) {
  int stride = gridDim.x * blockDim.x;
  for (int e = blockIdx.x * blockDim.x + threadIdx.x; e < NEDGES; e += stride) {
    int d = ei[NEDGES + e];
    int pos = atomicAdd(&cursor[d], 1);
    esrc[rowptr[d] + pos] = ei[e];
  }
}

// ---------------------------------------------------------------------------
// Gather-sum per destination node (64-lane wave) over bf16 h, fused GCNII
// support mix, bf16 output.
// ---------------------------------------------------------------------------
__global__ __launch_bounds__(256) void agg_support_k(const unsigned short* __restrict__ hb,
                                                     const int* __restrict__ rowptr,
                                                     const int* __restrict__ esrc,
                                                     const float* __restrict__ x0,
                                                     unsigned short* __restrict__ supp_bf) {
  const int lane = threadIdx.x & 63;
  const int d = (blockIdx.x * blockDim.x + threadIdx.x) >> 6;
  if (d >= NNODES) return;
  const int beg = rowptr[d];
  const int end = rowptr[d + 1];
  const int off = lane * 4;                  // 4 bf16 = 8 B per lane

  float4 acc = make_float4(0.f, 0.f, 0.f, 0.f);
  int e = beg;
  for (; e + 1 < end; e += 2) {
    int s0 = esrc[e];
    int s1 = esrc[e + 1];
    ushort4 u0 = *(const ushort4*)(hb + (long long)s0 * HIDDIM + off);
    ushort4 u1 = *(const ushort4*)(hb + (long long)s1 * HIDDIM + off);
    acc.x += bf2f(u0.x) + bf2f(u1.x);
    acc.y += bf2f(u0.y) + bf2f(u1.y);
    acc.z += bf2f(u0.z) + bf2f(u1.z);
    acc.w += bf2f(u0.w) + bf2f(u1.w);
  }
  if (e < end) {
    int s0 = esrc[e];
    ushort4 u0 = *(const ushort4*)(hb + (long long)s0 * HIDDIM + off);
    acc.x += bf2f(u0.x); acc.y += bf2f(u0.y);
    acc.z += bf2f(u0.z); acc.w += bf2f(u0.w);
  }

  ushort4 uh = *(const ushort4*)(hb + (long long)d * HIDDIM + off);
  float4 xx = *(const float4*)(x0 + (long long)d * HIDDIM + off);
  ushort4 o;
  o.x = f2bf((1.f - kAlpha) * (bf2f(uh.x) + acc.x) + kAlpha * xx.x);
  o.y = f2bf((1.f - kAlpha) * (bf2f(uh.y) + acc.y) + kAlpha * xx.y);
  o.z = f2bf((1.f - kAlpha) * (bf2f(uh.z) + acc.z) + kAlpha * xx.z);
  o.w = f2bf((1.f - kAlpha) * (bf2f(uh.w) + acc.w) + kAlpha * xx.w);
  *(ushort4*)(supp_bf + (long long)d * HIDDIM + off) = o;
}

// ---------------------------------------------------------------------------
extern "C" void kernel_launch(void* const* d_in, const int* in_sizes, int n_in,
                              void* d_out, int out_size, void* d_ws, size_t ws_size,
                              hipStream_t stream) {
  // inputs: s0, s1, x_0, W_pre, gamma, beta_bn, W_op, edge_index, drop_prob, training
  const float* s1    = (const float*)d_in[1];
  const float* x0    = (const float*)d_in[2];
  const float* W_pre = (const float*)d_in[3];
  const float* gamma = (const float*)d_in[4];
  const float* betab = (const float*)d_in[5];
  const float* W_op  = (const float*)d_in[6];
  const int*   ei    = (const int*)d_in[7];
  float* out = (float*)d_out;

  const size_t NH = (size_t)NNODES * HIDDIM;            // 12.8M elements
  unsigned short* hbf   = (unsigned short*)d_ws;        // 25.6 MB (bf16 h)
  unsigned short* s1bf  = hbf + NH;                     // 25.6 MB
  unsigned short* supbf = s1bf + NH;                    // 25.6 MB
  float* colsum   = (float*)(supbf + NH);               // 256
  float* colsumsq = colsum + HIDDIM;
  float* scale    = colsumsq + HIDDIM;
  float* shift    = scale + HIDDIM;
  unsigned short* wpre_t = (unsigned short*)(shift + HIDDIM);  // 128 KB
  unsigned short* wop_t  = wpre_t + 65536;              // 128 KB
  int* deg    = (int*)(wop_t + 65536);                  // 50000
  int* cursor = deg + NNODES;                           // 50000
  int* rowptr = cursor + NNODES;                        // 50001
  int* esrc   = rowptr + (NNODES + 1);                  // 800000

  hipMemsetAsync(colsum, 0, 2 * HIDDIM * sizeof(float), stream);
  hipMemsetAsync(deg, 0, 2 * NNODES * sizeof(int), stream);    // deg + cursor

  conv_wt_k<<<256, 256, 0, stream>>>(W_pre, wpre_t);
  conv_wt_k<<<256, 256, 0, stream>>>(W_op, wop_t);
  conv_bf_k<<<2048, 256, 0, stream>>>(s1, s1bf, (int)(NH / 4));

  const int gx = (NNODES + 127) / 128;
  gemm_bf16_k<0><<<gx, 256, 0, stream>>>(s1bf, wpre_t, hbf, nullptr, colsum, colsumsq, NNODES);
  bn_finalize_k<<<1, HIDDIM, 0, stream>>>(colsum, colsumsq, gamma, betab, scale, shift);
  bn_relu_bf_k<<<2048, 256, 0, stream>>>(hbf, scale, shift);

  hist_k<<<1024, 256, 0, stream>>>(ei, deg);
  scan_k<<<1, 1024, 0, stream>>>(deg, rowptr);
  fill_k<<<1024, 256, 0, stream>>>(ei, rowptr, cursor, esrc);
  agg_support_k<<<(NNODES * 64 + 255) / 256, 256, 0, stream>>>(hbf, rowptr, esrc, x0, supbf);

  gemm_bf16_k<1><<<gx, 256, 0, stream>>>(supbf, wop_t, out, supbf, nullptr, nullptr, NNODES);
}

// Round 6
// 232.241 us; speedup vs baseline: 13.0161x; 1.4790x over previous
//
#include <hip/hip_runtime.h>

#define NNODES 50000
#define NEDGES 800000
#define HIDDIM 256
#define NB_SCAN 196   // ceil(NNODES/256)

constexpr float kAlpha = 0.1f;
constexpr float kBnEps = 1e-5f;
constexpr float kBeta  = 0.40546510810816438198f;   // log(1.5)

typedef __attribute__((ext_vector_type(8))) short  bf16x8;   // 8 bf16 in 4 VGPRs
typedef __attribute__((ext_vector_type(4))) float  f32x4;

static __device__ __forceinline__ unsigned short f2bf(float f) {
  unsigned u = __float_as_uint(f);
  u = (u + 0x7FFFu + ((u >> 16) & 1u)) >> 16;      // RTNE
  return (unsigned short)u;
}
static __device__ __forceinline__ float bf2f(unsigned short h) {
  return __uint_as_float(((unsigned)h) << 16);
}

// ---------------------------------------------------------------------------
// W[k][n] fp32 -> Wt[n][k] bf16 (transpose + convert; tiny)
// ---------------------------------------------------------------------------
__global__ __launch_bounds__(256) void conv_wt_k(const float* __restrict__ W,
                                                 unsigned short* __restrict__ Wt) {
  int n = blockIdx.x, k = threadIdx.x;
  Wt[n * 256 + k] = f2bf(W[k * 256 + n]);
}

// ---------------------------------------------------------------------------
// bf16 MFMA GEMM: C = A[M,256] @ B[256,256], Bt transposed [n][k].
// 128x256 tile, BK=64, 4 waves (2x2, each 64r x 128c), XOR-swizzled LDS.
// MODE 0: A is fp32 (converted in staging); C bf16 raw + column sum/sumsq
// MODE 1: A is bf16; C fp32 = relu((1-beta)*S + beta*(A@B)), S bf16
// ---------------------------------------------------------------------------
template<int MODE>
__global__ __launch_bounds__(256) void gemm_bf16_k(
    const void* __restrict__ Ain,
    const unsigned short* __restrict__ Bt,   // [256][256] bf16, Bt[n][k]
    void* __restrict__ Cout,                 // MODE0: bf16; MODE1: float
    const unsigned short* __restrict__ S,    // MODE1: residual bf16
    float* __restrict__ colsum,
    float* __restrict__ colsumsq,
    int M) {
  __shared__ unsigned short Al[128 * 64];    // 16 KB, row stride 128 B
  __shared__ unsigned short Bl[256 * 64];    // 32 KB
  __shared__ float cs[4][128], cq[4][128];   // MODE0 column-stat reduction

  const int t    = threadIdx.x;
  const int lane = t & 63;
  const int wid  = t >> 6;
  const int wr   = wid >> 1;                 // wave row (0/1): rows wr*64..+63
  const int wc   = wid & 1;                  // wave col (0/1): cols wc*128..+127
  const int row0 = blockIdx.x * 128;

  f32x4 acc[4][8] = {};

  const int srow = t & 127;                  // A staging row
  const int sseg = t >> 7;                   // A staging k-half (32 k each)
  const int arow = row0 + srow;
  const bool aok = arow < M;
  const int swzA = (srow & 7) << 4;
  const int swzB = (t & 7) << 4;

  for (int ks = 0; ks < 4; ++ks) {
    if (ks) __syncthreads();
    const int k0 = ks * 64;
    // ---- stage A (zero-pad OOB rows): thread -> half-row, 4x16B chunks ----
    if (MODE == 0) {
      const float* src = (const float*)Ain + (size_t)arow * 256 + k0 + sseg * 32;
#pragma unroll
      for (int c = 0; c < 4; ++c) {
        int byteoff = srow * 128 + ((sseg * 64 + c * 16) ^ swzA);
        bf16x8 v = {};
        if (aok) {
          float4 p = *(const float4*)(src + c * 8);
          float4 q = *(const float4*)(src + c * 8 + 4);
          v[0] = (short)f2bf(p.x); v[1] = (short)f2bf(p.y);
          v[2] = (short)f2bf(p.z); v[3] = (short)f2bf(p.w);
          v[4] = (short)f2bf(q.x); v[5] = (short)f2bf(q.y);
          v[6] = (short)f2bf(q.z); v[7] = (short)f2bf(q.w);
        }
        *(bf16x8*)((char*)Al + byteoff) = v;
      }
    } else {
      const unsigned short* src = (const unsigned short*)Ain + (size_t)arow * 256 + k0 + sseg * 32;
#pragma unroll
      for (int c = 0; c < 4; ++c) {
        int byteoff = srow * 128 + ((sseg * 64 + c * 16) ^ swzA);
        bf16x8 v = {};
        if (aok) v = *(const bf16x8*)(src + c * 8);
        *(bf16x8*)((char*)Al + byteoff) = v;
      }
    }
    // ---- stage B: thread -> full row t (256 rows), 8x16B chunks ----
    {
      const unsigned short* src = Bt + (size_t)t * 256 + k0;
#pragma unroll
      for (int c = 0; c < 8; ++c) {
        int byteoff = t * 128 + ((c * 16) ^ swzB);
        *(bf16x8*)((char*)Bl + byteoff) = *(const bf16x8*)(src + c * 8);
      }
    }
    __syncthreads();
    // ---- compute: 2 k-slices x 32 MFMA ----
#pragma unroll
    for (int kk = 0; kk < 2; ++kk) {
      const int koff = kk * 64 + ((lane >> 4) * 16);   // byte offset in row
      bf16x8 af[4], bfr[8];
#pragma unroll
      for (int m = 0; m < 4; ++m) {
        int row = wr * 64 + m * 16 + (lane & 15);
        af[m] = *(const bf16x8*)((char*)Al + row * 128 + (koff ^ ((row & 7) << 4)));
      }
#pragma unroll
      for (int n = 0; n < 8; ++n) {
        int nr = wc * 128 + n * 16 + (lane & 15);
        bfr[n] = *(const bf16x8*)((char*)Bl + nr * 128 + (koff ^ ((nr & 7) << 4)));
      }
#pragma unroll
      for (int m = 0; m < 4; ++m)
#pragma unroll
        for (int n = 0; n < 8; ++n)
          acc[m][n] = __builtin_amdgcn_mfma_f32_16x16x32_bf16(af[m], bfr[n], acc[m][n], 0, 0, 0);
    }
  }

  // ---- MODE 0: column sum / sumsq (OOB rows contributed exact zeros) ----
  if (MODE == 0) {
#pragma unroll
    for (int n = 0; n < 8; ++n) {
      float s = 0.f, q = 0.f;
#pragma unroll
      for (int m = 0; m < 4; ++m)
#pragma unroll
        for (int r = 0; r < 4; ++r) {
          float v = acc[m][n][r];
          s += v; q += v * v;
        }
      s += __shfl_xor(s, 16); s += __shfl_xor(s, 32);
      q += __shfl_xor(q, 16); q += __shfl_xor(q, 32);
      if (lane < 16) { cs[wid][n * 16 + lane] = s; cq[wid][n * 16 + lane] = q; }
    }
    __syncthreads();
    {
      int wcg = t >> 7;                      // column half (0/1)
      int lc  = t & 127;
      atomicAdd(&colsum[t],   cs[wcg][lc] + cs[wcg + 2][lc]);
      atomicAdd(&colsumsq[t], cq[wcg][lc] + cq[wcg + 2][lc]);
    }
  }

  // ---- store (C/D layout: col=lane&15, row=(lane>>4)*4+r) ----
#pragma unroll
  for (int m = 0; m < 4; ++m) {
    int rbase = row0 + wr * 64 + m * 16 + (lane >> 4) * 4;
#pragma unroll
    for (int r = 0; r < 4; ++r) {
      int row = rbase + r;
      if (row < M) {
#pragma unroll
        for (int n = 0; n < 8; ++n) {
          int col = wc * 128 + n * 16 + (lane & 15);
          float v = acc[m][n][r];
          if (MODE == 0) {
            ((unsigned short*)Cout)[(size_t)row * 256 + col] = f2bf(v);
          } else {
            float s = bf2f(S[(size_t)row * 256 + col]);
            ((float*)Cout)[(size_t)row * 256 + col] =
                fmaxf((1.f - kBeta) * s + kBeta * v, 0.f);
          }
        }
      }
    }
  }
}

// ---------------------------------------------------------------------------
__global__ __launch_bounds__(256) void bn_finalize_k(const float* __restrict__ colsum,
                                                     const float* __restrict__ colsumsq,
                                                     const float* __restrict__ gamma,
                                                     const float* __restrict__ beta_bn,
                                                     float* __restrict__ scale,
                                                     float* __restrict__ shift) {
  int j = threadIdx.x;
  float inv_n = 1.0f / (float)NNODES;
  float mu  = colsum[j] * inv_n;
  float var = colsumsq[j] * inv_n - mu * mu;
  float rstd = rsqrtf(var + kBnEps);
  float sc = gamma[j] * rstd;
  scale[j] = sc;
  shift[j] = beta_bn[j] - mu * sc;
}

// ---------------------------------------------------------------------------
// CSR build: degree histogram -> 3-phase parallel scan -> bucket src ids
// ---------------------------------------------------------------------------
__global__ __launch_bounds__(256) void hist_k(const int* __restrict__ ei,
                                              int* __restrict__ deg) {
  int stride = gridDim.x * blockDim.x;
  for (int e = blockIdx.x * blockDim.x + threadIdx.x; e < NEDGES; e += stride)
    atomicAdd(&deg[ei[NEDGES + e]], 1);
}

__global__ __launch_bounds__(256) void scanA_k(const int* __restrict__ deg,
                                               int* __restrict__ rowptr,
                                               int* __restrict__ blocksum) {
  __shared__ int sh[256];
  const int t = threadIdx.x;
  const int idx = blockIdx.x * 256 + t;
  int v = (idx < NNODES) ? deg[idx] : 0;
  sh[t] = v;
  __syncthreads();
  for (int off = 1; off < 256; off <<= 1) {
    int x = (t >= off) ? sh[t - off] : 0;
    __syncthreads();
    sh[t] += x;
    __syncthreads();
  }
  if (idx < NNODES) rowptr[idx] = sh[t] - v;      // exclusive within block
  if (t == 255) blocksum[blockIdx.x] = sh[255];
}

__global__ __launch_bounds__(256) void scanB_k(const int* __restrict__ blocksum,
                                               int* __restrict__ blockoff,
                                               int* __restrict__ rowptr) {
  __shared__ int sh[256];
  const int t = threadIdx.x;
  int v = (t < NB_SCAN) ? blocksum[t] : 0;
  sh[t] = v;
  __syncthreads();
  for (int off = 1; off < 256; off <<= 1) {
    int x = (t >= off) ? sh[t - off] : 0;
    __syncthreads();
    sh[t] += x;
    __syncthreads();
  }
  blockoff[t] = sh[t] - v;                        // exclusive block offset
  if (t == 255) rowptr[NNODES] = sh[255];         // grand total (=NEDGES)
}

__global__ __launch_bounds__(256) void scanC_k(int* __restrict__ rowptr,
                                               const int* __restrict__ blockoff) {
  const int idx = blockIdx.x * 256 + threadIdx.x;
  if (idx < NNODES) rowptr[idx] += blockoff[blockIdx.x];
}

__global__ __launch_bounds__(256) void fill_k(const int* __restrict__ ei,
                                              const int* __restrict__ rowptr,
                                              int* __restrict__ cursor,
                                              int* __restrict__ esrc) {
  int stride = gridDim.x * blockDim.x;
  for (int e = blockIdx.x * blockDim.x + threadIdx.x; e < NEDGES; e += stride) {
    int d = ei[NEDGES + e];
    int pos = atomicAdd(&cursor[d], 1);
    esrc[rowptr[d] + pos] = ei[e];
  }
}

// ---------------------------------------------------------------------------
// Gather-sum per destination node with FUSED BatchNorm+ReLU on each gathered
// row, then GCNII support mix. Half-wave (32 lanes x 16B) per node; gathers
// unrolled x4 for ILP. h is raw GEMM1 output (bf16, pre-BN).
// ---------------------------------------------------------------------------
__global__ __launch_bounds__(256) void agg_bn_support_k(
    const unsigned short* __restrict__ hb,   // [N][256] raw bf16
    const int* __restrict__ rowptr,
    const int* __restrict__ esrc,
    const float* __restrict__ x0,
    const float* __restrict__ scale,
    const float* __restrict__ shift,
    unsigned short* __restrict__ supp_bf) {
  const int hw   = threadIdx.x >> 5;         // half-wave in block (0..7)
  const int lane = threadIdx.x & 31;
  const int d    = blockIdx.x * 8 + hw;      // grid sized exactly: no guard needed
  const int off  = lane * 8;                 // 8 bf16 elems = 16 B per lane

  float sc[8], sh[8];
  *(float4*)&sc[0] = *(const float4*)(scale + off);
  *(float4*)&sc[4] = *(const float4*)(scale + off + 4);
  *(float4*)&sh[0] = *(const float4*)(shift + off);
  *(float4*)&sh[4] = *(const float4*)(shift + off + 4);

  const int beg = rowptr[d];
  const int end = rowptr[d + 1];
  float acc[8] = {0.f, 0.f, 0.f, 0.f, 0.f, 0.f, 0.f, 0.f};

  int e = beg;
  for (; e + 3 < end; e += 4) {
    int s0 = esrc[e], s1 = esrc[e + 1], s2 = esrc[e + 2], s3 = esrc[e + 3];
    bf16x8 v0 = *(const bf16x8*)(hb + (size_t)s0 * HIDDIM + off);
    bf16x8 v1 = *(const bf16x8*)(hb + (size_t)s1 * HIDDIM + off);
    bf16x8 v2 = *(const bf16x8*)(hb + (size_t)s2 * HIDDIM + off);
    bf16x8 v3 = *(const bf16x8*)(hb + (size_t)s3 * HIDDIM + off);
#pragma unroll
    for (int j = 0; j < 8; ++j) {
      acc[j] += fmaxf(fmaf(bf2f((unsigned short)v0[j]), sc[j], sh[j]), 0.f)
              + fmaxf(fmaf(bf2f((unsigned short)v1[j]), sc[j], sh[j]), 0.f)
              + fmaxf(fmaf(bf2f((unsigned short)v2[j]), sc[j], sh[j]), 0.f)
              + fmaxf(fmaf(bf2f((unsigned short)v3[j]), sc[j], sh[j]), 0.f);
    }
  }
  for (; e < end; ++e) {
    int s0 = esrc[e];
    bf16x8 v0 = *(const bf16x8*)(hb + (size_t)s0 * HIDDIM + off);
#pragma unroll
    for (int j = 0; j < 8; ++j)
      acc[j] += fmaxf(fmaf(bf2f((unsigned short)v0[j]), sc[j], sh[j]), 0.f);
  }

  // self term + initial residual
  bf16x8 vd = *(const bf16x8*)(hb + (size_t)d * HIDDIM + off);
  float4 xa = *(const float4*)(x0 + (size_t)d * HIDDIM + off);
  float4 xb = *(const float4*)(x0 + (size_t)d * HIDDIM + off + 4);
  float xs[8] = {xa.x, xa.y, xa.z, xa.w, xb.x, xb.y, xb.z, xb.w};
  bf16x8 o;
#pragma unroll
  for (int j = 0; j < 8; ++j) {
    float hv = fmaxf(fmaf(bf2f((unsigned short)vd[j]), sc[j], sh[j]), 0.f);
    o[j] = (short)f2bf((1.f - kAlpha) * (hv + acc[j]) + kAlpha * xs[j]);
  }
  *(bf16x8*)(supp_bf + (size_t)d * HIDDIM + off) = o;
}

// ---------------------------------------------------------------------------
extern "C" void kernel_launch(void* const* d_in, const int* in_sizes, int n_in,
                              void* d_out, int out_size, void* d_ws, size_t ws_size,
                              hipStream_t stream) {
  // inputs: s0, s1, x_0, W_pre, gamma, beta_bn, W_op, edge_index, drop_prob, training
  const float* s1    = (const float*)d_in[1];
  const float* x0    = (const float*)d_in[2];
  const float* W_pre = (const float*)d_in[3];
  const float* gamma = (const float*)d_in[4];
  const float* betab = (const float*)d_in[5];
  const float* W_op  = (const float*)d_in[6];
  const int*   ei    = (const int*)d_in[7];
  float* out = (float*)d_out;

  const size_t NH = (size_t)NNODES * HIDDIM;            // 12.8M elements
  unsigned short* hbf   = (unsigned short*)d_ws;        // 25.6 MB (raw bf16 h)
  unsigned short* supbf = hbf + NH;                     // 25.6 MB
  float* colsum   = (float*)(supbf + NH);               // 256
  float* colsumsq = colsum + HIDDIM;
  float* scale    = colsumsq + HIDDIM;
  float* shift    = scale + HIDDIM;
  unsigned short* wpre_t = (unsigned short*)(shift + HIDDIM);  // 128 KB
  unsigned short* wop_t  = wpre_t + 65536;              // 128 KB
  int* deg      = (int*)(wop_t + 65536);                // 50000
  int* cursor   = deg + NNODES;                         // 50000
  int* rowptr   = cursor + NNODES;                      // 50001
  int* esrc     = rowptr + (NNODES + 1);                // 800000
  int* blocksum = esrc + NEDGES;                        // 256
  int* blockoff = blocksum + 256;                       // 256

  hipMemsetAsync(colsum, 0, 2 * HIDDIM * sizeof(float), stream);
  hipMemsetAsync(deg, 0, 2 * NNODES * sizeof(int), stream);    // deg + cursor

  conv_wt_k<<<256, 256, 0, stream>>>(W_pre, wpre_t);
  conv_wt_k<<<256, 256, 0, stream>>>(W_op, wop_t);

  // CSR build
  hist_k<<<1024, 256, 0, stream>>>(ei, deg);
  scanA_k<<<NB_SCAN, 256, 0, stream>>>(deg, rowptr, blocksum);
  scanB_k<<<1, 256, 0, stream>>>(blocksum, blockoff, rowptr);
  scanC_k<<<NB_SCAN, 256, 0, stream>>>(rowptr, blockoff);
  fill_k<<<1024, 256, 0, stream>>>(ei, rowptr, cursor, esrc);

  // GEMM1 (fp32 A converted in staging) -> raw bf16 h + BN stats
  const int gx = (NNODES + 127) / 128;
  gemm_bf16_k<0><<<gx, 256, 0, stream>>>(s1, wpre_t, hbf, nullptr, colsum, colsumsq, NNODES);
  bn_finalize_k<<<1, HIDDIM, 0, stream>>>(colsum, colsumsq, gamma, betab, scale, shift);

  // gather + fused BN/ReLU + support mix
  agg_bn_support_k<<<(NNODES + 7) / 8, 256, 0, stream>>>(hbf, rowptr, esrc, x0,
                                                         scale, shift, supbf);

  // GEMM2 + GCNII epilogue
  gemm_bf16_k<1><<<gx, 256, 0, stream>>>(supbf, wop_t, out, supbf, nullptr, nullptr, NNODES);
}